// Round 1
// 788.812 us; speedup vs baseline: 1.0861x; 1.0861x over previous
//
#include <hip/hip_runtime.h>
#include <hip/hip_bf16.h>
#include <stdint.h>
#include <stddef.h>

#define SEQ 2048
#define BATCH 16
#define HID 1024
#define MM (SEQ*BATCH)   // 32768 rows
#define NN (3*HID)       // 3072 cols
#define KK HID           // 1024

typedef __bf16 bf16x8 __attribute__((ext_vector_type(8)));
typedef float floatx4 __attribute__((ext_vector_type(4)));

// ---------------- U element helpers (fp32 preferred, bf16 fallback) ----------
template <typename UT> __device__ inline void storeU(UT* p, float v);
template <> __device__ inline void storeU<float>(float* p, float v) { *p = v; }
template <> __device__ inline void storeU<__bf16>(__bf16* p, float v) { *p = (__bf16)v; }
template <typename UT> __device__ inline float loadU(const UT* p);
template <> __device__ inline float loadU<float>(const float* p) { return *p; }
template <> __device__ inline float loadU<__bf16>(const __bf16* p) { return (float)*p; }

// ---------------- cast input fp32 -> bf16 (Ap[M][K] row-major) ---------------
__global__ __launch_bounds__(256) void cast_a_kernel(const float* __restrict__ in,
                                                     __bf16* __restrict__ out) {
  size_t i = (size_t)blockIdx.x * 256 + threadIdx.x;   // one float4 per thread
  float4 v = ((const float4*)in)[i];
  typedef __bf16 bf16x4 __attribute__((ext_vector_type(4)));
  bf16x4 o;
  o[0] = (__bf16)v.x; o[1] = (__bf16)v.y; o[2] = (__bf16)v.z; o[3] = (__bf16)v.w;
  ((bf16x4*)out)[i] = o;
}

// ------------- transpose+cast weight [K][N] fp32 -> Wp [N][K] bf16 -----------
__global__ __launch_bounds__(256) void pack_w_kernel(const float* __restrict__ w,
                                                     __bf16* __restrict__ wp) {
  __shared__ float tile[32][33];
  int n0 = blockIdx.x * 32, k0 = blockIdx.y * 32;
  int tx = threadIdx.x, ty = threadIdx.y;   // 32 x 8
#pragma unroll
  for (int r = 0; r < 4; r++)
    tile[ty + 8*r][tx] = w[(size_t)(k0 + ty + 8*r) * NN + n0 + tx];
  __syncthreads();
#pragma unroll
  for (int r = 0; r < 4; r++)
    wp[(size_t)(n0 + ty + 8*r) * KK + k0 + tx] = (__bf16)tile[tx][ty + 8*r];
}

// ---------------- GEMM: U[row][n] = sum_k Ap[row][k] * Wp[n][k] --------------
// 128x128 tile, BK=64, 256 thr (4 waves 2x2, 64x64 each), 16x16x32 bf16 MFMA.
// LDS staged via global_load_lds(16B); XOR swizzle done on the global side.
// R2: XCD-aware bijective swizzle (6144 blocks % 8 == 0): each XCD gets 768
// consecutive tiles = 32 full A row-panels -> A panel (256KB) stays in its L2
// across the 24 column tiles instead of being re-fetched by all 8 XCDs.
template <typename UT>
__global__ __launch_bounds__(256) void gemm_kernel(const __bf16* __restrict__ A,
                                                   const __bf16* __restrict__ B,
                                                   UT* __restrict__ U) {
  __shared__ __align__(16) char smem[32768];   // A tile 16KB | B tile 16KB
  const int tid  = threadIdx.x;
  const int lane = tid & 63;
  const int wave = tid >> 6;

  // XCD swizzle: dispatch order is x-fastest; consecutive bids round-robin XCDs.
  const int bid = blockIdx.y * (NN / 128) + blockIdx.x;      // 0..6143
  const int nid = (bid & 7) * ((MM / 128) * (NN / 128) / 8) + (bid >> 3);
  const int tileN = (nid % (NN / 128)) * 128;
  const int tileM = (nid / (NN / 128)) * 128;

  // staging sources: slot s = j*256+tid ; s<1024 -> A chunk, else B chunk
  const char* gsrc[8];
  uint32_t    ldsoff[8];
#pragma unroll
  for (int j = 0; j < 8; j++) {
    int s   = j * 256 + tid;
    int isB = s >> 10;
    int s2  = s & 1023;
    int row = s2 >> 3;
    int cs  = s2 & 7;
    int kc  = cs ^ (row & 7);
    const __bf16* base = isB ? (B + (size_t)(tileN + row) * KK)
                             : (A + (size_t)(tileM + row) * KK);
    gsrc[j]   = (const char*)(base + kc * 8);
    ldsoff[j] = (uint32_t)(j * 4096 + wave * 1024);   // wave-uniform
  }

  const int wm = (wave >> 1) * 64;
  const int wn = (wave & 1) * 64;
  const int g  = lane >> 4;

  uint32_t aoff[4], boff[4];
#pragma unroll
  for (int i = 0; i < 4; i++) {
    int row  = wm + i * 16 + (lane & 15);
    aoff[i]  = (uint32_t)((row * 8 + (g ^ (row & 7))) * 16);
    int nrow = wn + i * 16 + (lane & 15);
    boff[i]  = (uint32_t)(16384 + (nrow * 8 + (g ^ (nrow & 7))) * 16);
  }

  floatx4 acc[4][4];
#pragma unroll
  for (int mi = 0; mi < 4; mi++)
#pragma unroll
    for (int ni = 0; ni < 4; ni++) acc[mi][ni] = (floatx4)0.0f;

  for (int it = 0; it < KK / 64; ++it) {
    __syncthreads();                 // prev compute done before overwrite
#pragma unroll
    for (int j = 0; j < 8; j++)
      __builtin_amdgcn_global_load_lds(
          (const __attribute__((address_space(1))) void*)(gsrc[j]),
          (__attribute__((address_space(3))) void*)(smem + ldsoff[j]), 16, 0, 0);
#pragma unroll
    for (int j = 0; j < 8; j++) gsrc[j] += 128;   // advance 64 bf16
    __syncthreads();                 // compiler drains vmcnt before barrier

#pragma unroll
    for (int ks = 0; ks < 2; ++ks) {
      bf16x8 a[4], b[4];
#pragma unroll
      for (int i = 0; i < 4; i++) {
        a[i] = *(const bf16x8*)(smem + (aoff[i] ^ (ks * 64)));
        b[i] = *(const bf16x8*)(smem + (boff[i] ^ (ks * 64)));
      }
#pragma unroll
      for (int mi = 0; mi < 4; mi++)
#pragma unroll
        for (int ni = 0; ni < 4; ni++)
          acc[mi][ni] = __builtin_amdgcn_mfma_f32_16x16x32_bf16(
              a[mi], b[ni], acc[mi][ni], 0, 0, 0);
    }
  }

  // epilogue: C/D layout col=lane&15, row=(lane>>4)*4+reg
  const int r0 = (lane >> 4) * 4;
  const int cc = lane & 15;
#pragma unroll
  for (int mi = 0; mi < 4; mi++)
#pragma unroll
    for (int ni = 0; ni < 4; ni++) {
      int col = tileN + wn + ni * 16 + cc;
#pragma unroll
      for (int r = 0; r < 4; r++) {
        int row = tileM + wm + mi * 16 + r0 + r;
        storeU(&U[(size_t)row * NN + col], acc[mi][ni][r]);
      }
    }
}

// ---------------- sequential SRU scan ----------------------------------------
__device__ inline float sigmoidf_fast(float z) {
  return __builtin_amdgcn_rcpf(1.0f + __expf(-z));
}

// R2: producer-consumer scan. The recurrence has only 16384 independent lanes
// = 1 wave/CU, and vmcnt in-flight capacity is PER-WAVE, so a single wave
// issuing its own loads is latency-capped (~2.4 TB/s). Split roles: 3 loader
// waves stage U+x into a double-buffered LDS ring via global_load_lds (3x the
// in-flight budget, zero VGPR round-trip); 1 compute wave runs the serial
// chain out of LDS. One timestep for a 64-h group is exactly 1KB
// (48x16B U + 16x16B x) = one global_load_lds per wave per step
// (wave-uniform LDS dst + lane*16; per-lane global addr picks U vs x).
// __syncthreads per 32-step chunk: its implicit vmcnt(0) drain on the
// producers is exactly the completion guarantee the consumer needs.
#define SCH 32   // steps per chunk; 2 x 32KB LDS ring

__global__ __launch_bounds__(256) void scan_pc_kernel(const float* __restrict__ U,
                                                      const float* __restrict__ x,
                                                      const float* __restrict__ bias,
                                                      float* __restrict__ out) {
  __shared__ __align__(16) char smem[2 * SCH * 1024];
  const int tid  = threadIdx.x;
  const int wave = tid >> 6;
  const int lane = tid & 63;
  const int b    = blockIdx.x >> 4;          // batch
  const int h0   = (blockIdx.x & 15) * 64;   // h-group base

  const char* const ub = (const char*)(U + (size_t)b * NN + 3 * h0);
  const char* const xb = (const char*)(x + (size_t)b * HID + h0);

  float b0 = 0.f, b1 = 0.f, c = 0.f;
  if (wave == 0) { b0 = bias[h0 + lane]; b1 = bias[HID + h0 + lane]; }

  // producer waves w in {1,2,3} stage steps s = w-1, w-1+3, ... of chunk ci
  auto issue = [&](int ci) {
    char* dst = smem + (ci & 1) * (SCH * 1024);
    for (int s = wave - 1; s < SCH; s += 3) {
      size_t t = (size_t)ci * SCH + s;
      const char* us = ub + t * (size_t)(BATCH * NN * 4);
      const char* xs = xb + t * (size_t)(BATCH * HID * 4);
      const char* src = (lane < 48) ? (us + lane * 16) : (xs + (lane - 48) * 16);
      __builtin_amdgcn_global_load_lds(
          (const __attribute__((address_space(1))) void*)src,
          (__attribute__((address_space(3))) void*)(dst + s * 1024), 16, 0, 0);
    }
  };

  if (wave > 0) issue(0);
  __syncthreads();   // drains producers' vmcnt -> chunk 0 resident

  for (int ci = 0; ci < SEQ / SCH; ++ci) {
    if (wave > 0) {
      if (ci + 1 < SEQ / SCH) issue(ci + 1);   // fill buf[(ci+1)&1]
    } else {
      const float* buf = (const float*)(smem + (ci & 1) * (SCH * 1024));
#pragma unroll 4
      for (int s = 0; s < SCH; ++s) {
        const float* p = buf + s * 256;        // 1KB per step
        float u0 = p[3 * lane];                // 3h stride: 2-way bank alias, free
        float u1 = p[3 * lane + 1];
        float u2 = p[3 * lane + 2];
        float xv = p[192 + lane];
        float f = sigmoidf_fast(u0 + b0 * c + b0);   // v0==b0 source quirk
        float r = sigmoidf_fast(u1 + b1 * c + b1);
        c = f * c + (1.0f - f) * u2;
        float ht = r * c + (1.0f - r) * xv;
        size_t o = (size_t)(ci * SCH + s) * (BATCH * HID) + (b * HID + h0 + lane);
        out[o] = ht;
        out[(size_t)SEQ * BATCH * HID + o] = c;
      }
    }
    __syncthreads();
  }
}

// legacy single-wave scan, kept for the bf16-U fallback path
template <typename UT>
__global__ __launch_bounds__(64) void scan_kernel(const UT* __restrict__ U,
                                                  const float* __restrict__ x,
                                                  const float* __restrict__ bias,
                                                  float* __restrict__ out) {
  int idx = blockIdx.x * 64 + threadIdx.x;   // 0..16383 over (b,h)
  int b = idx >> 10, h = idx & 1023;
  float b0 = bias[h], b1 = bias[HID + h];

  const UT*    up = U + (size_t)b * NN + 3 * h;   // step stride BATCH*NN
  const float* xp = x + idx;                      // step stride BATCH*HID
  float* Hout = out + idx;
  float* Cout = out + (size_t)SEQ * BATCH * HID + idx;

  constexpr int P = 16;
  float pu0[P], pu1[P], pu2[P], px[P];
#pragma unroll
  for (int i = 0; i < P; i++) {
    const UT* u = up + (size_t)i * (BATCH * NN);
    pu0[i] = loadU(u); pu1[i] = loadU(u + 1); pu2[i] = loadU(u + 2);
    px[i]  = xp[(size_t)i * (BATCH * HID)];
  }

  float c = 0.0f;
  int tt = 0;
  for (; tt < SEQ - P; tt += P) {
#pragma unroll
    for (int i = 0; i < P; i++) {
      int t = tt + i;
      float u0 = pu0[i], u1 = pu1[i], u2 = pu2[i], xv = px[i];
      const UT* u = up + (size_t)(t + P) * (BATCH * NN);
      pu0[i] = loadU(u); pu1[i] = loadU(u + 1); pu2[i] = loadU(u + 2);
      px[i]  = xp[(size_t)(t + P) * (BATCH * HID)];

      float f = sigmoidf_fast(u0 + b0 * c + b0);
      float r = sigmoidf_fast(u1 + b1 * c + b1);
      c = f * c + (1.0f - f) * u2;
      float ht = r * c + (1.0f - r) * xv;
      Cout[(size_t)t * (BATCH * HID)] = c;
      Hout[(size_t)t * (BATCH * HID)] = ht;
    }
  }
#pragma unroll
  for (int i = 0; i < P; i++) {
    int t = tt + i;
    float f = sigmoidf_fast(pu0[i] + b0 * c + b0);
    float r = sigmoidf_fast(pu1[i] + b1 * c + b1);
    c = f * c + (1.0f - f) * pu2[i];
    float ht = r * c + (1.0f - r) * px[i];
    Cout[(size_t)t * (BATCH * HID)] = c;
    Hout[(size_t)t * (BATCH * HID)] = ht;
  }
}

// ---------------- launch ------------------------------------------------------
extern "C" void kernel_launch(void* const* d_in, const int* in_sizes, int n_in,
                              void* d_out, int out_size, void* d_ws, size_t ws_size,
                              hipStream_t stream) {
  const float* input  = (const float*)d_in[0];
  const float* weight = (const float*)d_in[1];
  const float* bias   = (const float*)d_in[2];
  float* out = (float*)d_out;

  char* ws = (char*)d_ws;
  const size_t apB = (size_t)MM * KK * 2;   // 64 MiB
  const size_t wpB = (size_t)NN * KK * 2;   // 6 MiB
  const size_t uF  = (size_t)MM * NN * 4;   // 384 MiB fp32 U
  bool useF32 = ws_size >= uF + apB + wpB;
  size_t uB = useF32 ? uF : uF / 2;

  void*   Uv = (void*)ws;
  __bf16* Ap = (__bf16*)(ws + uB);
  __bf16* Wp = (__bf16*)(ws + uB + apB);

  cast_a_kernel<<<(MM * KK) / 4 / 256, 256, 0, stream>>>(input, Ap);
  pack_w_kernel<<<dim3(NN / 32, KK / 32), dim3(32, 8), 0, stream>>>(weight, Wp);

  if (useF32) {
    gemm_kernel<float><<<dim3(NN / 128, MM / 128), 256, 0, stream>>>(Ap, Wp, (float*)Uv);
    scan_pc_kernel<<<BATCH * 16, 256, 0, stream>>>((const float*)Uv, input, bias, out);
  } else {
    gemm_kernel<__bf16><<<dim3(NN / 128, MM / 128), 256, 0, stream>>>(Ap, Wp, (__bf16*)Uv);
    scan_kernel<__bf16><<<(BATCH * HID) / 64, 64, 0, stream>>>((const __bf16*)Uv, input, bias, out);
  }
}

// Round 2
// 783.769 us; speedup vs baseline: 1.0931x; 1.0064x over previous
//
#include <hip/hip_runtime.h>
#include <hip/hip_bf16.h>
#include <stdint.h>
#include <stddef.h>

#define SEQ 2048
#define BATCH 16
#define HID 1024
#define MM (SEQ*BATCH)   // 32768 rows
#define NN (3*HID)       // 3072 cols
#define KK HID           // 1024

typedef __bf16 bf16x8 __attribute__((ext_vector_type(8)));
typedef float floatx4 __attribute__((ext_vector_type(4)));

// ---------------- U element helpers (fp32 preferred, bf16 fallback) ----------
template <typename UT> __device__ inline void storeU(UT* p, float v);
template <> __device__ inline void storeU<float>(float* p, float v) { *p = v; }
template <> __device__ inline void storeU<__bf16>(__bf16* p, float v) { *p = (__bf16)v; }
template <typename UT> __device__ inline float loadU(const UT* p);
template <> __device__ inline float loadU<float>(const float* p) { return *p; }
template <> __device__ inline float loadU<__bf16>(const __bf16* p) { return (float)*p; }

// ---------------- cast input fp32 -> bf16 (Ap[M][K] row-major) ---------------
__global__ __launch_bounds__(256) void cast_a_kernel(const float* __restrict__ in,
                                                     __bf16* __restrict__ out) {
  size_t i = (size_t)blockIdx.x * 256 + threadIdx.x;   // one float4 per thread
  float4 v = ((const float4*)in)[i];
  typedef __bf16 bf16x4 __attribute__((ext_vector_type(4)));
  bf16x4 o;
  o[0] = (__bf16)v.x; o[1] = (__bf16)v.y; o[2] = (__bf16)v.z; o[3] = (__bf16)v.w;
  ((bf16x4*)out)[i] = o;
}

// ------------- transpose+cast weight [K][N] fp32 -> Wp [N][K] bf16 -----------
__global__ __launch_bounds__(256) void pack_w_kernel(const float* __restrict__ w,
                                                     __bf16* __restrict__ wp) {
  __shared__ float tile[32][33];
  int n0 = blockIdx.x * 32, k0 = blockIdx.y * 32;
  int tx = threadIdx.x, ty = threadIdx.y;   // 32 x 8
#pragma unroll
  for (int r = 0; r < 4; r++)
    tile[ty + 8*r][tx] = w[(size_t)(k0 + ty + 8*r) * NN + n0 + tx];
  __syncthreads();
#pragma unroll
  for (int r = 0; r < 4; r++)
    wp[(size_t)(n0 + ty + 8*r) * KK + k0 + tx] = (__bf16)tile[tx][ty + 8*r];
}

// ---------------- GEMM: U[row][n] = sum_k Ap[row][k] * Wp[n][k] --------------
// 128x128 tile, BK=64, 256 thr (4 waves 2x2, 64x64 each), 16x16x32 bf16 MFMA.
// LDS staged via global_load_lds(16B); XOR swizzle done on the global side:
// stored chunk index = row*8 + (kc ^ (row&7))  -> max 2-way bank alias (free).
// R2 post-mortem: XCD-swizzle REGRESSED (FETCH 300->410MB, +15us): each XCD
// swept all 24 B-panels (6MB > 4MiB L2) per A-row -> B thrash. Default
// x-fastest order keeps B hot in L3 and shares the A panel across the 24
// consecutive column tiles. Reverted to the measured-good plain mapping.
template <typename UT>
__global__ __launch_bounds__(256) void gemm_kernel(const __bf16* __restrict__ A,
                                                   const __bf16* __restrict__ B,
                                                   UT* __restrict__ U) {
  __shared__ __align__(16) char smem[32768];   // A tile 16KB | B tile 16KB
  const int tid  = threadIdx.x;
  const int lane = tid & 63;
  const int wave = tid >> 6;
  const int tileN = blockIdx.x * 128;
  const int tileM = blockIdx.y * 128;

  // staging sources: slot s = j*256+tid ; s<1024 -> A chunk, else B chunk
  const char* gsrc[8];
  uint32_t    ldsoff[8];
#pragma unroll
  for (int j = 0; j < 8; j++) {
    int s   = j * 256 + tid;
    int isB = s >> 10;
    int s2  = s & 1023;
    int row = s2 >> 3;
    int cs  = s2 & 7;
    int kc  = cs ^ (row & 7);
    const __bf16* base = isB ? (B + (size_t)(tileN + row) * KK)
                             : (A + (size_t)(tileM + row) * KK);
    gsrc[j]   = (const char*)(base + kc * 8);
    ldsoff[j] = (uint32_t)(j * 4096 + wave * 1024);   // wave-uniform
  }

  const int wm = (wave >> 1) * 64;
  const int wn = (wave & 1) * 64;
  const int g  = lane >> 4;

  uint32_t aoff[4], boff[4];
#pragma unroll
  for (int i = 0; i < 4; i++) {
    int row  = wm + i * 16 + (lane & 15);
    aoff[i]  = (uint32_t)((row * 8 + (g ^ (row & 7))) * 16);
    int nrow = wn + i * 16 + (lane & 15);
    boff[i]  = (uint32_t)(16384 + (nrow * 8 + (g ^ (nrow & 7))) * 16);
  }

  floatx4 acc[4][4];
#pragma unroll
  for (int mi = 0; mi < 4; mi++)
#pragma unroll
    for (int ni = 0; ni < 4; ni++) acc[mi][ni] = (floatx4)0.0f;

  for (int it = 0; it < KK / 64; ++it) {
    __syncthreads();                 // prev compute done before overwrite
#pragma unroll
    for (int j = 0; j < 8; j++)
      __builtin_amdgcn_global_load_lds(
          (const __attribute__((address_space(1))) void*)(gsrc[j]),
          (__attribute__((address_space(3))) void*)(smem + ldsoff[j]), 16, 0, 0);
#pragma unroll
    for (int j = 0; j < 8; j++) gsrc[j] += 128;   // advance 64 bf16
    __syncthreads();                 // compiler drains vmcnt before barrier

#pragma unroll
    for (int ks = 0; ks < 2; ++ks) {
      bf16x8 a[4], b[4];
#pragma unroll
      for (int i = 0; i < 4; i++) {
        a[i] = *(const bf16x8*)(smem + (aoff[i] ^ (ks * 64)));
        b[i] = *(const bf16x8*)(smem + (boff[i] ^ (ks * 64)));
      }
#pragma unroll
      for (int mi = 0; mi < 4; mi++)
#pragma unroll
        for (int ni = 0; ni < 4; ni++)
          acc[mi][ni] = __builtin_amdgcn_mfma_f32_16x16x32_bf16(
              a[mi], b[ni], acc[mi][ni], 0, 0, 0);
    }
  }

  // epilogue: C/D layout col=lane&15, row=(lane>>4)*4+reg
  const int r0 = (lane >> 4) * 4;
  const int cc = lane & 15;
#pragma unroll
  for (int mi = 0; mi < 4; mi++)
#pragma unroll
    for (int ni = 0; ni < 4; ni++) {
      int col = tileN + wn + ni * 16 + cc;
#pragma unroll
      for (int r = 0; r < 4; r++) {
        int row = tileM + wm + mi * 16 + r0 + r;
        storeU(&U[(size_t)row * NN + col], acc[mi][ni][r]);
      }
    }
}

// ---------------- sequential SRU scan ----------------------------------------
__device__ inline float sigmoidf_fast(float z) {
  return __builtin_amdgcn_rcpf(1.0f + __expf(-z));
}

// R2: producer-consumer scan (3 loader waves -> LDS ring, 1 compute wave).
// R3: deepen the pipeline. __syncthreads() per chunk drained producer vmcnt
// to 0 -> only one 32KB chunk in flight per block -> per-chunk time = load
// latency (~2-3us), not bandwidth. T4 fix: ring of 4 chunk buffers, raw
// s_barrier, producers keep 2 chunks outstanding across every barrier via
// counted s_waitcnt vmcnt(2n) (n = 11/11/10 loads per producer per chunk;
// 20 is the safe bound). 3 chunks ahead ~= 96KB/block in flight, 24MB
// chip-wide -> above the ~13MB Little's-law need for 6.3TB/s.
// Ring hazard check: during phase ci the producers issue chunk ci+3 into
// buffer (ci+3)&3 == (ci-1)&3, whose reads finished in phase ci-1. Safe.
#define SCH 32             // steps per chunk
#define RING 4             // 4 x 32KB LDS ring
#define NCH (SEQ / SCH)    // 64 chunks

__global__ __launch_bounds__(256) void scan_pc_kernel(const float* __restrict__ U,
                                                      const float* __restrict__ x,
                                                      const float* __restrict__ bias,
                                                      float* __restrict__ out) {
  __shared__ __align__(16) char smem[RING * SCH * 1024];
  const int tid  = threadIdx.x;
  const int wave = tid >> 6;
  const int lane = tid & 63;
  const int b    = blockIdx.x >> 4;          // batch
  const int h0   = (blockIdx.x & 15) * 64;   // h-group base

  const char* const ub = (const char*)(U + (size_t)b * NN + 3 * h0);
  const char* const xb = (const char*)(x + (size_t)b * HID + h0);

  float b0 = 0.f, b1 = 0.f, c = 0.f;
  if (wave == 0) { b0 = bias[h0 + lane]; b1 = bias[HID + h0 + lane]; }

  // producer waves w in {1,2,3} stage steps s = w-1, w-1+3, ... of chunk ci.
  // One timestep = 1KB: 48 lanes x 16B of U + 16 lanes x 16B of x; LDS dst is
  // wave-uniform + lane*16 (m104 constraint), per-lane global addr picks U/x.
  auto issue = [&](int ci) {
    char* dst = smem + (ci & (RING - 1)) * (SCH * 1024);
    for (int s = wave - 1; s < SCH; s += 3) {
      size_t t = (size_t)ci * SCH + s;
      const char* us = ub + t * (size_t)(BATCH * NN * 4);
      const char* xs = xb + t * (size_t)(BATCH * HID * 4);
      const char* src = (lane < 48) ? (us + lane * 16) : (xs + (lane - 48) * 16);
      __builtin_amdgcn_global_load_lds(
          (const __attribute__((address_space(1))) void*)src,
          (__attribute__((address_space(3))) void*)(dst + s * 1024), 16, 0, 0);
    }
  };

  // prime: chunks 0,1,2 issued; drain to chunk 0 complete (<=2 chunks left)
  if (wave > 0) {
    issue(0); issue(1); issue(2);
    asm volatile("s_waitcnt vmcnt(20)" ::: "memory");
  }
  asm volatile("" ::: "memory");
  __builtin_amdgcn_s_barrier();
  asm volatile("" ::: "memory");

  for (int ci = 0; ci < NCH; ++ci) {
    if (wave > 0) {
      if (ci + 3 < NCH) {
        issue(ci + 3);
        asm volatile("s_waitcnt vmcnt(20)" ::: "memory");   // ci+1 landed
      } else if (ci + 2 < NCH) {
        asm volatile("s_waitcnt vmcnt(10)" ::: "memory");   // tail drain
      } else if (ci + 1 < NCH) {
        asm volatile("s_waitcnt vmcnt(0)" ::: "memory");
      }
    } else {
      const float* buf = (const float*)(smem + (ci & (RING - 1)) * (SCH * 1024));
#pragma unroll 4
      for (int s = 0; s < SCH; ++s) {
        const float* p = buf + s * 256;        // 1KB per step
        float u0 = p[3 * lane];                // 3h stride: 2-way bank alias, free
        float u1 = p[3 * lane + 1];
        float u2 = p[3 * lane + 2];
        float xv = p[192 + lane];
        float f = sigmoidf_fast(u0 + b0 * c + b0);   // v0==b0 source quirk
        float r = sigmoidf_fast(u1 + b1 * c + b1);
        c = f * c + (1.0f - f) * u2;
        float ht = r * c + (1.0f - r) * xv;
        size_t o = (size_t)(ci * SCH + s) * (BATCH * HID) + (b * HID + h0 + lane);
        out[o] = ht;
        out[(size_t)SEQ * BATCH * HID + o] = c;
      }
    }
    asm volatile("" ::: "memory");
    __builtin_amdgcn_s_barrier();
    asm volatile("" ::: "memory");
  }
}

// legacy single-wave scan, kept for the bf16-U fallback path
template <typename UT>
__global__ __launch_bounds__(64) void scan_kernel(const UT* __restrict__ U,
                                                  const float* __restrict__ x,
                                                  const float* __restrict__ bias,
                                                  float* __restrict__ out) {
  int idx = blockIdx.x * 64 + threadIdx.x;   // 0..16383 over (b,h)
  int b = idx >> 10, h = idx & 1023;
  float b0 = bias[h], b1 = bias[HID + h];

  const UT*    up = U + (size_t)b * NN + 3 * h;   // step stride BATCH*NN
  const float* xp = x + idx;                      // step stride BATCH*HID
  float* Hout = out + idx;
  float* Cout = out + (size_t)SEQ * BATCH * HID + idx;

  constexpr int P = 16;
  float pu0[P], pu1[P], pu2[P], px[P];
#pragma unroll
  for (int i = 0; i < P; i++) {
    const UT* u = up + (size_t)i * (BATCH * NN);
    pu0[i] = loadU(u); pu1[i] = loadU(u + 1); pu2[i] = loadU(u + 2);
    px[i]  = xp[(size_t)i * (BATCH * HID)];
  }

  float c = 0.0f;
  int tt = 0;
  for (; tt < SEQ - P; tt += P) {
#pragma unroll
    for (int i = 0; i < P; i++) {
      int t = tt + i;
      float u0 = pu0[i], u1 = pu1[i], u2 = pu2[i], xv = px[i];
      const UT* u = up + (size_t)(t + P) * (BATCH * NN);
      pu0[i] = loadU(u); pu1[i] = loadU(u + 1); pu2[i] = loadU(u + 2);
      px[i]  = xp[(size_t)(t + P) * (BATCH * HID)];

      float f = sigmoidf_fast(u0 + b0 * c + b0);
      float r = sigmoidf_fast(u1 + b1 * c + b1);
      c = f * c + (1.0f - f) * u2;
      float ht = r * c + (1.0f - r) * xv;
      Cout[(size_t)t * (BATCH * HID)] = c;
      Hout[(size_t)t * (BATCH * HID)] = ht;
    }
  }
#pragma unroll
  for (int i = 0; i < P; i++) {
    int t = tt + i;
    float f = sigmoidf_fast(pu0[i] + b0 * c + b0);
    float r = sigmoidf_fast(pu1[i] + b1 * c + b1);
    c = f * c + (1.0f - f) * pu2[i];
    float ht = r * c + (1.0f - r) * px[i];
    Cout[(size_t)t * (BATCH * HID)] = c;
    Hout[(size_t)t * (BATCH * HID)] = ht;
  }
}

// ---------------- launch ------------------------------------------------------
extern "C" void kernel_launch(void* const* d_in, const int* in_sizes, int n_in,
                              void* d_out, int out_size, void* d_ws, size_t ws_size,
                              hipStream_t stream) {
  const float* input  = (const float*)d_in[0];
  const float* weight = (const float*)d_in[1];
  const float* bias   = (const float*)d_in[2];
  float* out = (float*)d_out;

  char* ws = (char*)d_ws;
  const size_t apB = (size_t)MM * KK * 2;   // 64 MiB
  const size_t wpB = (size_t)NN * KK * 2;   // 6 MiB
  const size_t uF  = (size_t)MM * NN * 4;   // 384 MiB fp32 U
  bool useF32 = ws_size >= uF + apB + wpB;
  size_t uB = useF32 ? uF : uF / 2;

  void*   Uv = (void*)ws;
  __bf16* Ap = (__bf16*)(ws + uB);
  __bf16* Wp = (__bf16*)(ws + uB + apB);

  cast_a_kernel<<<(MM * KK) / 4 / 256, 256, 0, stream>>>(input, Ap);
  pack_w_kernel<<<dim3(NN / 32, KK / 32), dim3(32, 8), 0, stream>>>(weight, Wp);

  if (useF32) {
    gemm_kernel<float><<<dim3(NN / 128, MM / 128), 256, 0, stream>>>(Ap, Wp, (float*)Uv);
    scan_pc_kernel<<<BATCH * 16, 256, 0, stream>>>((const float*)Uv, input, bias, out);
  } else {
    gemm_kernel<__bf16><<<dim3(NN / 128, MM / 128), 256, 0, stream>>>(Ap, Wp, (__bf16*)Uv);
    scan_kernel<__bf16><<<(BATCH * HID) / 64, 64, 0, stream>>>((const __bf16*)Uv, input, bias, out);
  }
}

// Round 3
// 734.982 us; speedup vs baseline: 1.1657x; 1.0664x over previous
//
#include <hip/hip_runtime.h>
#include <hip/hip_bf16.h>
#include <stdint.h>
#include <stddef.h>

#define SEQ 2048
#define BATCH 16
#define HID 1024
#define MM (SEQ*BATCH)   // 32768 rows
#define NN (3*HID)       // 3072 cols
#define KK HID           // 1024

typedef __bf16 bf16x8 __attribute__((ext_vector_type(8)));
typedef float floatx4 __attribute__((ext_vector_type(4)));

// ---------------- U element helpers (fp32 preferred, bf16 fallback) ----------
template <typename UT> __device__ inline void storeU(UT* p, float v);
template <> __device__ inline void storeU<float>(float* p, float v) { *p = v; }
template <> __device__ inline void storeU<__bf16>(__bf16* p, float v) { *p = (__bf16)v; }
template <typename UT> __device__ inline float loadU(const UT* p);
template <> __device__ inline float loadU<float>(const float* p) { return *p; }
template <> __device__ inline float loadU<__bf16>(const __bf16* p) { return (float)*p; }

// ---------------- cast input fp32 -> bf16 (Ap[M][K] row-major) ---------------
__global__ __launch_bounds__(256) void cast_a_kernel(const float* __restrict__ in,
                                                     __bf16* __restrict__ out) {
  size_t i = (size_t)blockIdx.x * 256 + threadIdx.x;   // one float4 per thread
  float4 v = ((const float4*)in)[i];
  typedef __bf16 bf16x4 __attribute__((ext_vector_type(4)));
  bf16x4 o;
  o[0] = (__bf16)v.x; o[1] = (__bf16)v.y; o[2] = (__bf16)v.z; o[3] = (__bf16)v.w;
  ((bf16x4*)out)[i] = o;
}

// ------------- transpose+cast weight [K][N] fp32 -> Wp [N][K] bf16 -----------
__global__ __launch_bounds__(256) void pack_w_kernel(const float* __restrict__ w,
                                                     __bf16* __restrict__ wp) {
  __shared__ float tile[32][33];
  int n0 = blockIdx.x * 32, k0 = blockIdx.y * 32;
  int tx = threadIdx.x, ty = threadIdx.y;   // 32 x 8
#pragma unroll
  for (int r = 0; r < 4; r++)
    tile[ty + 8*r][tx] = w[(size_t)(k0 + ty + 8*r) * NN + n0 + tx];
  __syncthreads();
#pragma unroll
  for (int r = 0; r < 4; r++)
    wp[(size_t)(n0 + ty + 8*r) * KK + k0 + tx] = (__bf16)tile[tx][ty + 8*r];
}

// ---------------- GEMM 256x256, 8-phase counted-vmcnt schedule ---------------
// R3: port of the verified 256^2 8-phase template (T2+T3+T4+T5). 512 thr =
// 8 waves (2M x 4N), per-wave output 128x64 with INTERLEAVED frag ownership
// (wave wr owns rows mi*32+wr*16, wave wc owns cols ni*64+wc*16) so every
// wave reads both LDS A-halves and both B-halves -> half-tile deadness works.
// LDS 128KB: 2 K-tile buffers x (A 32KB | B 32KB), chunk-XOR swizzle as in
// the verified 128^2 kernel (0 bank conflicts measured).
// Quadrant order per K-tile: (A0B0)(A1B0)(A1B1)(A0B1); A/B frags shared by
// consecutive quadrants stay in regs (32 ds_read_b128 per K-tile, not 48).
// Staging: one 16KB half-tile per phase (2 global_load_lds/thread):
//   p0: A0(kt+1)  p1: B1(kt+1)  p2: B0(kt+2)  p3: A1(kt+2)
// Ledger (verified): each stage targets a region dead at the previous phase's
// end barrier; each half lands >=4 phases before first use; per-phase
// vmcnt(6) with the stage issued BEFORE the wait (sched_barrier-pinned)
// publishes the <=u-4 guarantee across the u-1 barrier (cross-wave safe).
// Tail: kt=14 waits 6,6,4,2; kt=15 drains once.
#define G256_PHASE(ktv, a, b, LA, LB)                                         \
  do {                                                                        \
    const char* cb = (const char*)smem + (((ktv) & 1) * 65536);               \
    if (LA) {                                                                 \
      _Pragma("unroll") for (int i = 0; i < 4; ++i) {                         \
        af[i][0] = *(const bf16x8*)(cb + aoff[(a)*4 + i]);                    \
        af[i][1] = *(const bf16x8*)(cb + (aoff[(a)*4 + i] ^ 64u));            \
      }                                                                       \
    }                                                                         \
    if (LB) {                                                                 \
      _Pragma("unroll") for (int n = 0; n < 2; ++n) {                         \
        bf[n][0] = *(const bf16x8*)(cb + boff[(b)*2 + n]);                    \
        bf[n][1] = *(const bf16x8*)(cb + (boff[(b)*2 + n] ^ 64u));            \
      }                                                                       \
    }                                                                         \
    asm volatile("" ::: "memory");                                            \
    __builtin_amdgcn_s_barrier();                                             \
    asm volatile("" ::: "memory");                                            \
    __builtin_amdgcn_s_setprio(1);                                            \
    _Pragma("unroll") for (int i = 0; i < 4; ++i)                             \
      _Pragma("unroll") for (int n = 0; n < 2; ++n) {                         \
        acc[(a)*4+i][(b)*2+n] = __builtin_amdgcn_mfma_f32_16x16x32_bf16(      \
            af[i][0], bf[n][0], acc[(a)*4+i][(b)*2+n], 0, 0, 0);              \
        acc[(a)*4+i][(b)*2+n] = __builtin_amdgcn_mfma_f32_16x16x32_bf16(      \
            af[i][1], bf[n][1], acc[(a)*4+i][(b)*2+n], 0, 0, 0);              \
      }                                                                       \
    __builtin_amdgcn_s_setprio(0);                                            \
    asm volatile("" ::: "memory");                                            \
    __builtin_amdgcn_s_barrier();                                             \
    asm volatile("" ::: "memory");                                            \
  } while (0)

template <typename UT>
__global__ __launch_bounds__(512, 2) void gemm256_kernel(const __bf16* __restrict__ A,
                                                         const __bf16* __restrict__ B,
                                                         UT* __restrict__ U) {
  __shared__ __align__(16) char smem[131072];   // 2 bufs x (A 32KB | B 32KB)
  const int tid  = threadIdx.x;
  const int lane = tid & 63;
  const int wave = tid >> 6;
  const int wr   = wave >> 2;      // 0..1 (M)
  const int wc   = wave & 3;       // 0..3 (N)
  const int g    = lane >> 4;      // 0..3
  const int tileN = blockIdx.x * 256;
  const int tileM = blockIdx.y * 256;

  // ---- staging: one call = one 16KB half-tile (2 x global_load_lds/thread)
  // chunk slot s = j*512 + tid; row = h*128 + (s>>3); stored chunk kc is the
  // global-side XOR pre-swizzle (kc j-independent since j*64 % 8 == 0).
  const int      kc16 = ((tid & 7) ^ ((tid >> 3) & 7)) << 4;
  const uint32_t ldsl = (uint32_t)(wave * 1024 + (lane << 4));
  auto stage = [&](int t, int isB, int h) {
    const char* gb = (const char*)(isB ? B : A);
    int rb = (isB ? tileN : tileM) + h * 128 + (tid >> 3);
    const char* src = gb + (size_t)rb * (KK * 2) + t * 128 + kc16;
    uint32_t dst = (uint32_t)((t & 1) * 65536 + isB * 32768 + h * 16384) + ldsl;
    __builtin_amdgcn_global_load_lds(
        (const __attribute__((address_space(1))) void*)src,
        (__attribute__((address_space(3))) void*)(smem + dst), 16, 0, 0);
    __builtin_amdgcn_global_load_lds(
        (const __attribute__((address_space(1))) void*)(src + 64 * (KK * 2)),
        (__attribute__((address_space(3))) void*)(smem + dst + 8192), 16, 0, 0);
  };

  // ---- per-lane fragment read offsets (within a buffer) ----
  const int xl = lane & 15;
  const int sw = g ^ (lane & 7);            // (row&7) == lane&7 for all frags
  uint32_t aoff[8], boff[4];
#pragma unroll
  for (int mi = 0; mi < 8; ++mi) {
    int row = mi * 32 + wr * 16 + xl;
    aoff[mi] = (uint32_t)((row * 8 + sw) * 16);
  }
#pragma unroll
  for (int ni = 0; ni < 4; ++ni) {
    int rn = ni * 64 + wc * 16 + xl;
    boff[ni] = (uint32_t)(32768 + (rn * 8 + sw) * 16);
  }

  floatx4 acc[8][4];
#pragma unroll
  for (int mi = 0; mi < 8; ++mi)
#pragma unroll
    for (int ni = 0; ni < 4; ++ni) acc[mi][ni] = (floatx4)0.0f;
  bf16x8 af[4][2], bf[2][2];

  // ---- prologue: tile0 fully + t1 B0, t1 A1 (their nominal slots are g=-2,-1)
  stage(0, 0, 0); stage(0, 0, 1); stage(0, 1, 0); stage(0, 1, 1);
  stage(1, 1, 0); stage(1, 0, 1);
  __builtin_amdgcn_sched_barrier(0);
  asm volatile("s_waitcnt vmcnt(4)" ::: "memory");   // tile0's 8 loads landed
  asm volatile("" ::: "memory");
  __builtin_amdgcn_s_barrier();
  asm volatile("" ::: "memory");

  for (int kt = 0; kt < 16; ++kt) {
    // p0: reads A0,B0 of kt | stage A0(kt+1)
    if (kt + 1 < 16) stage(kt + 1, 0, 0);
    __builtin_amdgcn_sched_barrier(0);
    if (kt < 15) { asm volatile("s_waitcnt vmcnt(6)" ::: "memory"); }
    else         { asm volatile("s_waitcnt vmcnt(0)" ::: "memory"); }
    G256_PHASE(kt, 0, 0, 1, 1);
    // p1: reads A1 (B0 reused in regs) | stage B1(kt+1)
    if (kt + 1 < 16) stage(kt + 1, 1, 1);
    __builtin_amdgcn_sched_barrier(0);
    if (kt < 15) { asm volatile("s_waitcnt vmcnt(6)" ::: "memory"); }
    G256_PHASE(kt, 1, 0, 1, 0);
    // p2: reads B1 (A1 reused) | stage B0(kt+2)
    if (kt + 2 < 16) stage(kt + 2, 1, 0);
    __builtin_amdgcn_sched_barrier(0);
    if (kt < 14)       { asm volatile("s_waitcnt vmcnt(6)" ::: "memory"); }
    else if (kt == 14) { asm volatile("s_waitcnt vmcnt(4)" ::: "memory"); }
    G256_PHASE(kt, 1, 1, 0, 1);
    // p3: reads A0 (B1 reused) | stage A1(kt+2)
    if (kt + 2 < 16) stage(kt + 2, 0, 1);
    __builtin_amdgcn_sched_barrier(0);
    if (kt < 14)       { asm volatile("s_waitcnt vmcnt(6)" ::: "memory"); }
    else if (kt == 14) { asm volatile("s_waitcnt vmcnt(2)" ::: "memory"); }
    G256_PHASE(kt, 0, 1, 1, 0);
  }

  // epilogue: C/D layout col=lane&15, row=(lane>>4)*4+reg
  const int r0 = (lane >> 4) * 4;
  const int cc = lane & 15;
#pragma unroll
  for (int mi = 0; mi < 8; ++mi)
#pragma unroll
    for (int ni = 0; ni < 4; ++ni) {
      int col = tileN + ni * 64 + wc * 16 + cc;
#pragma unroll
      for (int r = 0; r < 4; ++r) {
        int row = tileM + mi * 32 + wr * 16 + r0 + r;
        storeU(&U[(size_t)row * NN + col], acc[mi][ni][r]);
      }
    }
}

// ---------------- sequential SRU scan ----------------------------------------
__device__ inline float sigmoidf_fast(float z) {
  return __builtin_amdgcn_rcpf(1.0f + __expf(-z));
}

// R2/R3: producer-consumer scan (3 loader waves -> LDS ring, 1 compute wave),
// ring of 4 chunks, counted vmcnt so 2 chunks stay in flight across barriers.
#define SCH 32             // steps per chunk
#define RING 4             // 4 x 32KB LDS ring
#define NCH (SEQ / SCH)    // 64 chunks

__global__ __launch_bounds__(256) void scan_pc_kernel(const float* __restrict__ U,
                                                      const float* __restrict__ x,
                                                      const float* __restrict__ bias,
                                                      float* __restrict__ out) {
  __shared__ __align__(16) char smem[RING * SCH * 1024];
  const int tid  = threadIdx.x;
  const int wave = tid >> 6;
  const int lane = tid & 63;
  const int b    = blockIdx.x >> 4;          // batch
  const int h0   = (blockIdx.x & 15) * 64;   // h-group base

  const char* const ub = (const char*)(U + (size_t)b * NN + 3 * h0);
  const char* const xb = (const char*)(x + (size_t)b * HID + h0);

  float b0 = 0.f, b1 = 0.f, c = 0.f;
  if (wave == 0) { b0 = bias[h0 + lane]; b1 = bias[HID + h0 + lane]; }

  auto issue = [&](int ci) {
    char* dst = smem + (ci & (RING - 1)) * (SCH * 1024);
    for (int s = wave - 1; s < SCH; s += 3) {
      size_t t = (size_t)ci * SCH + s;
      const char* us = ub + t * (size_t)(BATCH * NN * 4);
      const char* xs = xb + t * (size_t)(BATCH * HID * 4);
      const char* src = (lane < 48) ? (us + lane * 16) : (xs + (lane - 48) * 16);
      __builtin_amdgcn_global_load_lds(
          (const __attribute__((address_space(1))) void*)src,
          (__attribute__((address_space(3))) void*)(dst + s * 1024), 16, 0, 0);
    }
  };

  if (wave > 0) {
    issue(0); issue(1); issue(2);
    asm volatile("s_waitcnt vmcnt(20)" ::: "memory");
  }
  asm volatile("" ::: "memory");
  __builtin_amdgcn_s_barrier();
  asm volatile("" ::: "memory");

  for (int ci = 0; ci < NCH; ++ci) {
    if (wave > 0) {
      if (ci + 3 < NCH) {
        issue(ci + 3);
        asm volatile("s_waitcnt vmcnt(20)" ::: "memory");   // ci+1 landed
      } else if (ci + 2 < NCH) {
        asm volatile("s_waitcnt vmcnt(10)" ::: "memory");   // tail drain
      } else if (ci + 1 < NCH) {
        asm volatile("s_waitcnt vmcnt(0)" ::: "memory");
      }
    } else {
      const float* buf = (const float*)(smem + (ci & (RING - 1)) * (SCH * 1024));
#pragma unroll 4
      for (int s = 0; s < SCH; ++s) {
        const float* p = buf + s * 256;        // 1KB per step
        float u0 = p[3 * lane];                // 3h stride: 2-way bank alias, free
        float u1 = p[3 * lane + 1];
        float u2 = p[3 * lane + 2];
        float xv = p[192 + lane];
        float f = sigmoidf_fast(u0 + b0 * c + b0);   // v0==b0 source quirk
        float r = sigmoidf_fast(u1 + b1 * c + b1);
        c = f * c + (1.0f - f) * u2;
        float ht = r * c + (1.0f - r) * xv;
        size_t o = (size_t)(ci * SCH + s) * (BATCH * HID) + (b * HID + h0 + lane);
        out[o] = ht;
        out[(size_t)SEQ * BATCH * HID + o] = c;
      }
    }
    asm volatile("" ::: "memory");
    __builtin_amdgcn_s_barrier();
    asm volatile("" ::: "memory");
  }
}

// ---------------- launch ------------------------------------------------------
extern "C" void kernel_launch(void* const* d_in, const int* in_sizes, int n_in,
                              void* d_out, int out_size, void* d_ws, size_t ws_size,
                              hipStream_t stream) {
  const float* input  = (const float*)d_in[0];
  const float* weight = (const float*)d_in[1];
  const float* bias   = (const float*)d_in[2];
  float* out = (float*)d_out;

  char* ws = (char*)d_ws;
  const size_t apB = (size_t)MM * KK * 2;   // 64 MiB
  const size_t wpB = (size_t)NN * KK * 2;   // 6 MiB
  const size_t uF  = (size_t)MM * NN * 4;   // 384 MiB fp32 U
  bool useF32 = ws_size >= uF + apB + wpB;
  size_t uB = useF32 ? uF : uF / 2;

  void*   Uv = (void*)ws;
  __bf16* Ap = (__bf16*)(ws + uB);
  __bf16* Wp = (__bf16*)(ws + uB + apB);

  cast_a_kernel<<<(MM * KK) / 4 / 256, 256, 0, stream>>>(input, Ap);
  pack_w_kernel<<<dim3(NN / 32, KK / 32), dim3(32, 8), 0, stream>>>(weight, Wp);

  if (useF32) {
    gemm256_kernel<float><<<dim3(NN / 256, MM / 256), 512, 0, stream>>>(Ap, Wp, (float*)Uv);
    scan_pc_kernel<<<BATCH * 16, 256, 0, stream>>>((const float*)Uv, input, bias, out);
  } else {
    gemm256_kernel<__bf16><<<dim3(NN / 256, MM / 256), 512, 0, stream>>>(Ap, Wp, (__bf16*)Uv);
    scan_pc_kernel<<<BATCH * 16, 256, 0, stream>>>((const float*)Uv, input, bias, out);
  }
}